// Round 2
// baseline (3736.204 us; speedup 1.0000x reference)
//
#include <hip/hip_runtime.h>
#include <stdint.h>

#define BB 4
#define NN 8192
#define SS 2048
#define KK 16
#define IND 64
#define CIN 67
#define OD 128

typedef unsigned int   u32;
typedef unsigned long long u64;

// ---------------- prep: pack xyz into float4(x,y,z,|p|^2) (rn ops, matches np sum order) -
__global__ __launch_bounds__(256) void k_prep(const float* __restrict__ xyz,
                                              float4* __restrict__ pts){
  int i = blockIdx.x * 256 + threadIdx.x;
  if (i >= BB*NN) return;
  float x = xyz[3*i+0];
  float y = xyz[3*i+1];
  float z = xyz[3*i+2];
  float x2 = __fadd_rn(__fadd_rn(__fmul_rn(x,x), __fmul_rn(y,y)), __fmul_rn(z,z));
  pts[i] = make_float4(x,y,z,x2);
}

// ---------------- FPS: one block per batch, exact np fp32 arithmetic --------------------
#define FPT 512
#define PPT (NN/FPT)   // 16 points per thread
__global__ __launch_bounds__(FPT) void k_fps(const float4* __restrict__ pts,
                                             float* __restrict__ out_xyz,
                                             float* __restrict__ fps_xyz){
  __shared__ float sredD[FPT/64];
  __shared__ int   sredI[FPT/64];
  __shared__ float scx, scy, scz;
  int b = blockIdx.x;
  int tid = threadIdx.x;
  const float4* P = pts + (size_t)b*NN;
  float px[PPT], py[PPT], pz[PPT], dd[PPT];
  #pragma unroll
  for (int j=0;j<PPT;j++){
    float4 p = P[tid*PPT + j];
    px[j]=p.x; py[j]=p.y; pz[j]=p.z;
    dd[j]=1e10f;
  }
  if (tid==0){
    float4 p0 = P[0];
    size_t o = (size_t)b*SS*3;
    out_xyz[o]=p0.x; out_xyz[o+1]=p0.y; out_xyz[o+2]=p0.z;   // exact input values
    fps_xyz[o]=p0.x; fps_xyz[o+1]=p0.y; fps_xyz[o+2]=p0.z;
    scx=p0.x; scy=p0.y; scz=p0.z;
  }
  __syncthreads();
  float cx=scx, cy=scy, cz=scz;
  for (int it=1; it<SS; ++it){
    float bd=-1.0f; int bi=0;
    #pragma unroll
    for (int j=0;j<PPT;j++){
      // exactly ((dx*dx + dy*dy) + dz*dz), no FMA contraction (matches numpy fp32)
      float dx=__fsub_rn(px[j],cx), dy=__fsub_rn(py[j],cy), dz=__fsub_rn(pz[j],cz);
      float d = __fadd_rn(__fadd_rn(__fmul_rn(dx,dx),__fmul_rn(dy,dy)),__fmul_rn(dz,dz));
      float nd = fminf(dd[j], d);
      dd[j]=nd;
      if (nd > bd){ bd=nd; bi=tid*PPT+j; }   // strict > keeps lowest index (argmax-first)
    }
    #pragma unroll
    for (int m=32;m>=1;m>>=1){
      float od=__shfl_xor(bd,m,64);
      int   oi=__shfl_xor(bi,m,64);
      if (od>bd || (od==bd && oi<bi)){ bd=od; bi=oi; }
    }
    if ((tid&63)==0){ sredD[tid>>6]=bd; sredI[tid>>6]=bi; }
    __syncthreads();
    if (tid<64){
      const int W = FPT/64;
      float d2 = (tid<W)? sredD[tid] : -1.0f;
      int   i2 = (tid<W)? sredI[tid] : 0x7fffffff;
      #pragma unroll
      for (int m=W>>1;m>=1;m>>=1){
        float od=__shfl_xor(d2,m,64);
        int   oi=__shfl_xor(i2,m,64);
        if (od>d2 || (od==d2 && oi<i2)){ d2=od; i2=oi; }
      }
      if (tid==0){
        float4 pw = P[i2];                       // L2-resident fetch of winner coords
        size_t o=(size_t)b*SS*3 + (size_t)it*3;
        out_xyz[o]=pw.x; out_xyz[o+1]=pw.y; out_xyz[o+2]=pw.z;
        fps_xyz[o]=pw.x; fps_xyz[o+1]=pw.y; fps_xyz[o+2]=pw.z;
        scx=pw.x; scy=pw.y; scz=pw.z;
      }
    }
    __syncthreads();
    cx=scx; cy=scy; cz=scz;
  }
}

// ---------------- KNN: one wave per query, exact (q2+x2)-2dot, top-16 by (dist,idx) ----
__global__ __launch_bounds__(256) void k_knn(const float4* __restrict__ pts,
                                             const float* __restrict__ fps_xyz,
                                             int* __restrict__ knn_idx){
  int q = blockIdx.x*4 + (threadIdx.x>>6);
  int lane = threadIdx.x & 63;
  int b = q / SS;
  const float4* P = pts + (size_t)b*NN;
  float qx=fps_xyz[3*q], qy=fps_xyz[3*q+1], qz=fps_xyz[3*q+2];
  float q2 = __fadd_rn(__fadd_rn(__fmul_rn(qx,qx),__fmul_rn(qy,qy)),__fmul_rn(qz,qz));
  u64 key[KK];
  #pragma unroll
  for (int t=0;t<KK;t++) key[t] = ~0ull;
  for (int i=0;i<NN/64;i++){
    int n = i*64 + lane;             // coalesced float4 loads
    float4 p = P[n];
    float dot = __fadd_rn(__fadd_rn(__fmul_rn(qx,p.x),__fmul_rn(qy,p.y)),__fmul_rn(qz,p.z));
    float sd  = __fsub_rn(__fadd_rn(q2,p.w), __fmul_rn(2.0f,dot));
    u32 bu = __float_as_uint(sd);
    bu ^= (u32)((int)bu >> 31) | 0x80000000u;   // monotone float->uint (handles sd<0)
    u64 kk = ((u64)bu<<32) | (u32)n;
    if (kk < key[KK-1]){
      key[KK-1] = kk;
      #pragma unroll
      for (int t=KK-1;t>0;--t){      // one reverse bubble pass restores sortedness
        u64 a=key[t-1], c=key[t];
        bool sw = c < a;
        key[t-1] = sw? c : a;
        key[t]   = sw? a : c;
      }
    }
  }
  #pragma unroll 1
  for (int r=0;r<KK;r++){
    u64 m = key[0];
    #pragma unroll
    for (int mm=1;mm<64;mm<<=1){
      u64 om = __shfl_xor((unsigned long long)m, mm, 64);
      if (om < m) m = om;
    }
    if (lane==0) knn_idx[q*KK + r] = (int)(u32)m;
    if (key[0]==m){                  // unique keys -> exactly one lane pops
      #pragma unroll
      for (int t=0;t<KK-1;t++) key[t]=key[t+1];
      key[KK-1]=~0ull;
    }
  }
}

// ---------------- gather + MLP(67->128 relu ->128) + maxpool + LN, one wave/query ------
__global__ __launch_bounds__(256) void k_mlp(const float* __restrict__ feat,
                                             const float4* __restrict__ pts,
                                             const float* __restrict__ fps_xyz,
                                             const int* __restrict__ knn_idx,
                                             const float* __restrict__ W1, const float* __restrict__ b1,
                                             const float* __restrict__ W2, const float* __restrict__ b2,
                                             const float* __restrict__ g_ln, const float* __restrict__ b_ln,
                                             float* __restrict__ out_feat){
  __shared__ float gbuf[4][CIN][16];     // grouped: [j][k], wave-private slices
  __shared__ float hbuf[4][OD][20];      // h1: [channel][k], stride 20 (16B-aligned rows)
  int wid = threadIdx.x>>6, lane = threadIdx.x&63;
  int q = blockIdx.x*4 + wid;
  int b = q / SS;
  float* gw = &gbuf[wid][0][0];
  float* hw = &hbuf[wid][0][0];
  int k = lane & 15, part = lane >> 4;   // part in [0,4): 16 channels each
  int n = knn_idx[q*KK + k];
  {
    const float* fp = feat + ((size_t)b*NN + (size_t)n)*IND + part*16;
    float4 f0 = *(const float4*)(fp+0);
    float4 f1 = *(const float4*)(fp+4);
    float4 f2 = *(const float4*)(fp+8);
    float4 f3 = *(const float4*)(fp+12);
    float v[16] = {f0.x,f0.y,f0.z,f0.w, f1.x,f1.y,f1.z,f1.w,
                   f2.x,f2.y,f2.z,f2.w, f3.x,f3.y,f3.z,f3.w};
    #pragma unroll
    for (int c=0;c<16;c++) gw[(3+part*16+c)*16 + k] = v[c];
    if (part==0){
      float4 p = pts[(size_t)b*NN + n];
      gw[0*16+k] = __fsub_rn(p.x, fps_xyz[3*q+0]);  // exact rel coords (matches np fp32)
      gw[1*16+k] = __fsub_rn(p.y, fps_xyz[3*q+1]);
      gw[2*16+k] = __fsub_rn(p.z, fps_xyz[3*q+2]);
    }
  }
  __syncthreads();
  int o = lane;                          // this thread owns channels o and o+64
  float a0[16], a1[16];
  #pragma unroll
  for (int t=0;t<16;t++){ a0[t]=0.0f; a1[t]=0.0f; }
  #pragma unroll 4
  for (int j=0;j<CIN;j++){
    float w0 = W1[j*OD + o];
    float w1 = W1[j*OD + o + 64];
    #pragma unroll
    for (int t=0;t<16;t++){
      float gv = gw[j*16+t];             // LDS broadcast (merges to ds_read_b128)
      a0[t]=fmaf(gv,w0,a0[t]); a1[t]=fmaf(gv,w1,a1[t]);
    }
  }
  float bb0 = b1[o], bb1 = b1[o+64];
  #pragma unroll
  for (int t=0;t<16;t++){
    hw[o*20+t]      = fmaxf(a0[t]+bb0, 0.0f);
    hw[(o+64)*20+t] = fmaxf(a1[t]+bb1, 0.0f);
  }
  __syncthreads();
  float c0[16], c1[16];
  #pragma unroll
  for (int t=0;t<16;t++){ c0[t]=0.0f; c1[t]=0.0f; }
  #pragma unroll 4
  for (int j=0;j<OD;j++){
    float w0 = W2[j*OD + o];
    float w1 = W2[j*OD + o + 64];
    #pragma unroll
    for (int t=0;t<16;t++){
      float hv = hw[j*20+t];
      c0[t]=fmaf(hv,w0,c0[t]); c1[t]=fmaf(hv,w1,c1[t]);
    }
  }
  float m0=c0[0], m1=c1[0];
  #pragma unroll
  for (int t=1;t<16;t++){ m0=fmaxf(m0,c0[t]); m1=fmaxf(m1,c1[t]); }
  m0 += b2[o]; m1 += b2[o+64];           // fold bias after max (commutes with max)
  // LayerNorm over 128 channels (wave reduce)
  float ssum = m0+m1;
  #pragma unroll
  for (int mm=1;mm<64;mm<<=1) ssum += __shfl_xor(ssum,mm,64);
  float mean = ssum * (1.0f/128.0f);
  float d0=m0-mean, d1=m1-mean;
  float sq = d0*d0 + d1*d1;
  #pragma unroll
  for (int mm=1;mm<64;mm<<=1) sq += __shfl_xor(sq,mm,64);
  float var = sq * (1.0f/128.0f);
  float x = var + 1e-5f;
  float r = rsqrtf(x);
  r = r * (1.5f - 0.5f*x*r*r);           // one NR step -> ~1 ulp of 1/sqrt
  size_t ob = (size_t)q*OD;
  out_feat[ob+o]    = fmaf(d0*r, g_ln[o],    b_ln[o]);
  out_feat[ob+o+64] = fmaf(d1*r, g_ln[o+64], b_ln[o+64]);
}

extern "C" void kernel_launch(void* const* d_in, const int* in_sizes, int n_in,
                              void* d_out, int out_size, void* d_ws, size_t ws_size,
                              hipStream_t stream){
  const float* xyz  = (const float*)d_in[0];
  const float* feat = (const float*)d_in[1];
  const float* W1   = (const float*)d_in[2];
  const float* b1   = (const float*)d_in[3];
  const float* W2   = (const float*)d_in[4];
  const float* b2   = (const float*)d_in[5];
  const float* lg   = (const float*)d_in[6];
  const float* lb   = (const float*)d_in[7];
  float* out = (float*)d_out;
  char* ws = (char*)d_ws;
  float4* pts = (float4*)ws;                          // 512 KB
  float*  fpsx = (float*)(ws + 524288);               // 96 KB
  int*    kidx = (int*)(ws + 524288 + 98304);         // 512 KB
  float* out_xyz  = out;
  float* out_feat = out + (size_t)BB*SS*3;

  hipLaunchKernelGGL(k_prep, dim3((BB*NN+255)/256), dim3(256), 0, stream, xyz, pts);
  hipLaunchKernelGGL(k_fps,  dim3(BB),              dim3(FPT), 0, stream, pts, out_xyz, fpsx);
  hipLaunchKernelGGL(k_knn,  dim3(BB*SS/4),         dim3(256), 0, stream, pts, fpsx, kidx);
  hipLaunchKernelGGL(k_mlp,  dim3(BB*SS/4),         dim3(256), 0, stream,
                     feat, pts, fpsx, kidx, W1, b1, W2, b2, lg, lb, out_feat);
}

// Round 3
// 3378.020 us; speedup vs baseline: 1.1060x; 1.1060x over previous
//
#include <hip/hip_runtime.h>
#include <stdint.h>

#define BB 4
#define NN 8192
#define SS 2048
#define KK 16
#define IND 64
#define CIN 67
#define OD 128

typedef unsigned int   u32;
typedef unsigned long long u64;

// ---------------- prep: pack xyz into float4(x,y,z,|p|^2) (rn ops, matches np sum order) -
__global__ __launch_bounds__(256) void k_prep(const float* __restrict__ xyz,
                                              float4* __restrict__ pts){
  int i = blockIdx.x * 256 + threadIdx.x;
  if (i >= BB*NN) return;
  float x = xyz[3*i+0];
  float y = xyz[3*i+1];
  float z = xyz[3*i+2];
  float x2 = __fadd_rn(__fadd_rn(__fmul_rn(x,x), __fmul_rn(y,y)), __fmul_rn(z,z));
  pts[i] = make_float4(x,y,z,x2);
}

// ---------------- FPS v2: register dists, no VMEM in loop, ONE barrier per iter --------
#define FPT 512
#define PPT (NN/FPT)   // 16 points per thread
#define NW  (FPT/64)   // 8 waves
__global__ __launch_bounds__(FPT) void k_fps(const float4* __restrict__ pts,
                                             float* __restrict__ out_xyz,
                                             float* __restrict__ fps_xyz){
  __shared__ float4 res[SS];            // 32 KB: winner coords per iteration
  __shared__ u64    pkey[2][NW];        // double-buffered wave partials
  __shared__ float4 pxyz[2][NW];
  int b = blockIdx.x;
  int tid = threadIdx.x;
  int wid = tid >> 6, lane = tid & 63;
  const float4* P = pts + (size_t)b*NN;
  float px[PPT], py[PPT], pz[PPT], dd[PPT];
  #pragma unroll
  for (int j=0;j<PPT;j++){
    float4 p = P[tid*PPT + j];
    px[j]=p.x; py[j]=p.y; pz[j]=p.z;
    dd[j]=1e10f;
  }
  float4 p0 = P[0];                     // broadcast load (all lanes same addr)
  float cx=p0.x, cy=p0.y, cz=p0.z;
  if (tid==0) res[0] = p0;

  for (int it=1; it<SS; ++it){
    // ---- compute phase: exact numpy fp32, strict > keeps first (lowest) index --------
    float bd=-1.0f; int bj=0;
    #pragma unroll
    for (int j=0;j<PPT;j++){
      float dx=__fsub_rn(px[j],cx), dy=__fsub_rn(py[j],cy), dz=__fsub_rn(pz[j],cz);
      float d = __fadd_rn(__fadd_rn(__fmul_rn(dx,dx),__fmul_rn(dy,dy)),__fmul_rn(dz,dz));
      float nd = fminf(dd[j], d);
      dd[j]=nd;
      if (nd > bd){ bd=nd; bj=j; }
    }
    // key packs (dist, ~idx): u64 max == argmax with lowest-index tie-break (np argmax)
    u64 key = ((u64)__float_as_uint(bd) << 32) | (u32)~(u32)(tid*PPT + bj);
    #pragma unroll
    for (int m=1;m<64;m<<=1){
      u64 o = __shfl_xor(key, m, 64);
      if (o > key) key = o;
    }
    // wave-winner idx is wave-uniform; extract its coords (uniform j select + shfl)
    int widx = (int)~(u32)key;
    int jj = widx & (PPT-1);
    int ow_lane = (widx >> 4) & 63;     // owning tid = widx>>4; its lane within this wave
    float sx=px[0], sy=py[0], sz=pz[0];
    #pragma unroll
    for (int t=1;t<PPT;t++){ bool m=(jj==t); sx=m?px[t]:sx; sy=m?py[t]:sy; sz=m?pz[t]:sz; }
    sx = __shfl(sx, ow_lane, 64);
    sy = __shfl(sy, ow_lane, 64);
    sz = __shfl(sz, ow_lane, 64);
    if (lane==0){
      pkey[it&1][wid] = key;
      pxyz[it&1][wid] = make_float4(sx,sy,sz,0.0f);
    }
    __syncthreads();                    // only LDS traffic outstanding -> cheap waitcnt
    // ---- all threads redundantly reduce the NW partials (no second barrier) ----------
    u64 bk = pkey[it&1][0];
    float4 bc = pxyz[it&1][0];
    #pragma unroll
    for (int w=1;w<NW;w++){
      u64 k2 = pkey[it&1][w];
      float4 c2 = pxyz[it&1][w];
      if (k2 > bk){ bk=k2; bc=c2; }
    }
    cx=bc.x; cy=bc.y; cz=bc.z;
    if (tid==0) res[it] = bc;
  }
  __syncthreads();
  // ---- bulk store of all selected coords (both fp32 outputs) -----------------------
  for (int i=tid; i<SS; i+=FPT){
    float4 r = res[i];
    size_t o = (size_t)b*SS*3 + (size_t)i*3;
    out_xyz[o]=r.x; out_xyz[o+1]=r.y; out_xyz[o+2]=r.z;
    fps_xyz[o]=r.x; fps_xyz[o+1]=r.y; fps_xyz[o+2]=r.z;
  }
}

// ---------------- KNN: one wave per query, exact (q2+x2)-2dot, top-16 by (dist,idx) ----
__global__ __launch_bounds__(256) void k_knn(const float4* __restrict__ pts,
                                             const float* __restrict__ fps_xyz,
                                             int* __restrict__ knn_idx){
  int q = blockIdx.x*4 + (threadIdx.x>>6);
  int lane = threadIdx.x & 63;
  int b = q / SS;
  const float4* P = pts + (size_t)b*NN;
  float qx=fps_xyz[3*q], qy=fps_xyz[3*q+1], qz=fps_xyz[3*q+2];
  float q2 = __fadd_rn(__fadd_rn(__fmul_rn(qx,qx),__fmul_rn(qy,qy)),__fmul_rn(qz,qz));
  u64 key[KK];
  #pragma unroll
  for (int t=0;t<KK;t++) key[t] = ~0ull;
  for (int i=0;i<NN/64;i++){
    int n = i*64 + lane;             // coalesced float4 loads
    float4 p = P[n];
    float dot = __fadd_rn(__fadd_rn(__fmul_rn(qx,p.x),__fmul_rn(qy,p.y)),__fmul_rn(qz,p.z));
    float sd  = __fsub_rn(__fadd_rn(q2,p.w), __fmul_rn(2.0f,dot));
    u32 bu = __float_as_uint(sd);
    bu ^= (u32)((int)bu >> 31) | 0x80000000u;   // monotone float->uint (handles sd<0)
    u64 kk = ((u64)bu<<32) | (u32)n;
    if (kk < key[KK-1]){
      key[KK-1] = kk;
      #pragma unroll
      for (int t=KK-1;t>0;--t){      // one reverse bubble pass restores sortedness
        u64 a=key[t-1], c=key[t];
        bool sw = c < a;
        key[t-1] = sw? c : a;
        key[t]   = sw? a : c;
      }
    }
  }
  #pragma unroll 1
  for (int r=0;r<KK;r++){
    u64 m = key[0];
    #pragma unroll
    for (int mm=1;mm<64;mm<<=1){
      u64 om = __shfl_xor((unsigned long long)m, mm, 64);
      if (om < m) m = om;
    }
    if (lane==0) knn_idx[q*KK + r] = (int)(u32)m;
    if (key[0]==m){                  // unique keys -> exactly one lane pops
      #pragma unroll
      for (int t=0;t<KK-1;t++) key[t]=key[t+1];
      key[KK-1]=~0ull;
    }
  }
}

// ---------------- gather + MLP(67->128 relu ->128) + maxpool + LN, one wave/query ------
__global__ __launch_bounds__(256) void k_mlp(const float* __restrict__ feat,
                                             const float4* __restrict__ pts,
                                             const float* __restrict__ fps_xyz,
                                             const int* __restrict__ knn_idx,
                                             const float* __restrict__ W1, const float* __restrict__ b1,
                                             const float* __restrict__ W2, const float* __restrict__ b2,
                                             const float* __restrict__ g_ln, const float* __restrict__ b_ln,
                                             float* __restrict__ out_feat){
  __shared__ float gbuf[4][CIN][16];     // grouped: [j][k], wave-private slices
  __shared__ float hbuf[4][OD][20];      // h1: [channel][k], stride 20 (16B-aligned rows)
  int wid = threadIdx.x>>6, lane = threadIdx.x&63;
  int q = blockIdx.x*4 + wid;
  int b = q / SS;
  float* gw = &gbuf[wid][0][0];
  float* hw = &hbuf[wid][0][0];
  int k = lane & 15, part = lane >> 4;   // part in [0,4): 16 channels each
  int n = knn_idx[q*KK + k];
  {
    const float* fp = feat + ((size_t)b*NN + (size_t)n)*IND + part*16;
    float4 f0 = *(const float4*)(fp+0);
    float4 f1 = *(const float4*)(fp+4);
    float4 f2 = *(const float4*)(fp+8);
    float4 f3 = *(const float4*)(fp+12);
    float v[16] = {f0.x,f0.y,f0.z,f0.w, f1.x,f1.y,f1.z,f1.w,
                   f2.x,f2.y,f2.z,f2.w, f3.x,f3.y,f3.z,f3.w};
    #pragma unroll
    for (int c=0;c<16;c++) gw[(3+part*16+c)*16 + k] = v[c];
    if (part==0){
      float4 p = pts[(size_t)b*NN + n];
      gw[0*16+k] = __fsub_rn(p.x, fps_xyz[3*q+0]);  // exact rel coords (matches np fp32)
      gw[1*16+k] = __fsub_rn(p.y, fps_xyz[3*q+1]);
      gw[2*16+k] = __fsub_rn(p.z, fps_xyz[3*q+2]);
    }
  }
  __syncthreads();
  int o = lane;                          // this thread owns channels o and o+64
  float a0[16], a1[16];
  #pragma unroll
  for (int t=0;t<16;t++){ a0[t]=0.0f; a1[t]=0.0f; }
  #pragma unroll 4
  for (int j=0;j<CIN;j++){
    float w0 = W1[j*OD + o];
    float w1 = W1[j*OD + o + 64];
    #pragma unroll
    for (int t=0;t<16;t++){
      float gv = gw[j*16+t];             // LDS broadcast (merges to ds_read_b128)
      a0[t]=fmaf(gv,w0,a0[t]); a1[t]=fmaf(gv,w1,a1[t]);
    }
  }
  float bb0 = b1[o], bb1 = b1[o+64];
  #pragma unroll
  for (int t=0;t<16;t++){
    hw[o*20+t]      = fmaxf(a0[t]+bb0, 0.0f);
    hw[(o+64)*20+t] = fmaxf(a1[t]+bb1, 0.0f);
  }
  __syncthreads();
  float c0[16], c1[16];
  #pragma unroll
  for (int t=0;t<16;t++){ c0[t]=0.0f; c1[t]=0.0f; }
  #pragma unroll 4
  for (int j=0;j<OD;j++){
    float w0 = W2[j*OD + o];
    float w1 = W2[j*OD + o + 64];
    #pragma unroll
    for (int t=0;t<16;t++){
      float hv = hw[j*20+t];
      c0[t]=fmaf(hv,w0,c0[t]); c1[t]=fmaf(hv,w1,c1[t]);
    }
  }
  float m0=c0[0], m1=c1[0];
  #pragma unroll
  for (int t=1;t<16;t++){ m0=fmaxf(m0,c0[t]); m1=fmaxf(m1,c1[t]); }
  m0 += b2[o]; m1 += b2[o+64];           // fold bias after max (commutes with max)
  // LayerNorm over 128 channels (wave reduce)
  float ssum = m0+m1;
  #pragma unroll
  for (int mm=1;mm<64;mm<<=1) ssum += __shfl_xor(ssum,mm,64);
  float mean = ssum * (1.0f/128.0f);
  float d0=m0-mean, d1=m1-mean;
  float sq = d0*d0 + d1*d1;
  #pragma unroll
  for (int mm=1;mm<64;mm<<=1) sq += __shfl_xor(sq,mm,64);
  float var = sq * (1.0f/128.0f);
  float x = var + 1e-5f;
  float r = rsqrtf(x);
  r = r * (1.5f - 0.5f*x*r*r);           // one NR step -> ~1 ulp of 1/sqrt
  size_t ob = (size_t)q*OD;
  out_feat[ob+o]    = fmaf(d0*r, g_ln[o],    b_ln[o]);
  out_feat[ob+o+64] = fmaf(d1*r, g_ln[o+64], b_ln[o+64]);
}

extern "C" void kernel_launch(void* const* d_in, const int* in_sizes, int n_in,
                              void* d_out, int out_size, void* d_ws, size_t ws_size,
                              hipStream_t stream){
  const float* xyz  = (const float*)d_in[0];
  const float* feat = (const float*)d_in[1];
  const float* W1   = (const float*)d_in[2];
  const float* b1   = (const float*)d_in[3];
  const float* W2   = (const float*)d_in[4];
  const float* b2   = (const float*)d_in[5];
  const float* lg   = (const float*)d_in[6];
  const float* lb   = (const float*)d_in[7];
  float* out = (float*)d_out;
  char* ws = (char*)d_ws;
  float4* pts = (float4*)ws;                          // 512 KB
  float*  fpsx = (float*)(ws + 524288);               // 96 KB
  int*    kidx = (int*)(ws + 524288 + 98304);         // 512 KB
  float* out_xyz  = out;
  float* out_feat = out + (size_t)BB*SS*3;

  hipLaunchKernelGGL(k_prep, dim3((BB*NN+255)/256), dim3(256), 0, stream, xyz, pts);
  hipLaunchKernelGGL(k_fps,  dim3(BB),              dim3(FPT), 0, stream, pts, out_xyz, fpsx);
  hipLaunchKernelGGL(k_knn,  dim3(BB*SS/4),         dim3(256), 0, stream, pts, fpsx, kidx);
  hipLaunchKernelGGL(k_mlp,  dim3(BB*SS/4),         dim3(256), 0, stream,
                     feat, pts, fpsx, kidx, W1, b1, W2, b2, lg, lb, out_feat);
}

// Round 5
// 2910.462 us; speedup vs baseline: 1.2837x; 1.1606x over previous
//
#include <hip/hip_runtime.h>
#include <stdint.h>

#define BB 4
#define NN 8192
#define SS 2048
#define KK 16
#define IND 64
#define CIN 67
#define OD 128

typedef unsigned int   u32;
typedef unsigned long long u64;
typedef float f2 __attribute__((ext_vector_type(2)));

// ---------------- prep: pack xyz into float4(x,y,z,|p|^2) (rn ops, matches np sum order) -
__global__ __launch_bounds__(256) void k_prep(const float* __restrict__ xyz,
                                              float4* __restrict__ pts){
  int i = blockIdx.x * 256 + threadIdx.x;
  if (i >= BB*NN) return;
  float x = xyz[3*i+0];
  float y = xyz[3*i+1];
  float z = xyz[3*i+2];
  float x2 = __fadd_rn(__fadd_rn(__fmul_rn(x,x), __fmul_rn(y,y)), __fmul_rn(z,z));
  pts[i] = make_float4(x,y,z,x2);
}

// DPP helper: move x by DPP control, invalid lanes keep x (bound_ctrl=false -> old value)
template<int CTRL>
__device__ __forceinline__ float dpp_mv(float x){
  int xi = __builtin_bit_cast(int, x);
  int r  = __builtin_amdgcn_update_dpp(xi, xi, CTRL, 0xf, 0xf, false);
  return __builtin_bit_cast(float, r);
}

// ---------------- FPS v3: DPP wave argmax, one barrier/iter, no VMEM in loop ----------
#define FPT 512
#define PPT (NN/FPT)   // 16 points per thread
#define NW  (FPT/64)   // 8 waves
__global__ __launch_bounds__(FPT) void k_fps(const float4* __restrict__ pts,
                                             float* __restrict__ out_xyz,
                                             float* __restrict__ fps_xyz){
  #pragma clang fp contract(off)
  __shared__ float4 res[SS];            // 32 KB: winner coords per iteration
  __shared__ u64    pkey[2][NW];        // double-buffered wave partials
  __shared__ float4 pxyz[2][NW];
  int b = blockIdx.x;
  int tid = threadIdx.x;
  int wid = tid >> 6, lane = tid & 63;
  const float4* P = pts + (size_t)b*NN;
  f2 X[PPT/2], Y[PPT/2], Z[PPT/2], D[PPT/2];
  #pragma unroll
  for (int jp=0;jp<PPT/2;jp++){
    float4 p0 = P[tid*PPT + 2*jp];
    float4 p1 = P[tid*PPT + 2*jp + 1];
    X[jp] = (f2){p0.x, p1.x};
    Y[jp] = (f2){p0.y, p1.y};
    Z[jp] = (f2){p0.z, p1.z};
    D[jp] = (f2){1e10f, 1e10f};
  }
  float4 pz0 = P[0];                    // broadcast load
  float cx=pz0.x, cy=pz0.y, cz=pz0.z;
  if (tid==0) res[0] = pz0;

  for (int it=1; it<SS; ++it){
    // ---- compute: plain fp32 ops under contract(off) == numpy rn semantics ----------
    float bd=-1.0f; int bj=0;
    #pragma unroll
    for (int jp=0;jp<PPT/2;jp++){
      f2 dx = X[jp] - cx;
      f2 dy = Y[jp] - cy;
      f2 dz = Z[jp] - cz;
      f2 d  = ((dx*dx) + (dy*dy)) + (dz*dz);   // ((dx2+dy2)+dz2), no fma
      f2 nd;
      nd.x = fminf(D[jp].x, d.x);
      nd.y = fminf(D[jp].y, d.y);
      D[jp] = nd;
      if (nd.x > bd){ bd=nd.x; bj=2*jp;   }    // strict > keeps first (lowest) index
      if (nd.y > bd){ bd=nd.y; bj=2*jp+1; }
    }
    int bi = tid*PPT + bj;
    // ---- wave max via DPP (6 ops), winner lane via ballot (lowest lane = lowest idx) -
    float m = bd;
    m = fmaxf(m, dpp_mv<0x111>(m));   // row_shr:1
    m = fmaxf(m, dpp_mv<0x112>(m));   // row_shr:2
    m = fmaxf(m, dpp_mv<0x114>(m));   // row_shr:4
    m = fmaxf(m, dpp_mv<0x118>(m));   // row_shr:8
    m = fmaxf(m, dpp_mv<0x142>(m));   // row_bcast:15
    m = fmaxf(m, dpp_mv<0x143>(m));   // row_bcast:31  -> lane 63 = wave max
    float wmax = __builtin_bit_cast(float,
        __builtin_amdgcn_readlane(__builtin_bit_cast(int, m), 63));
    u64 ball = __ballot(bd == wmax);
    int wl = __ffsll((unsigned long long)ball) - 1;  // lowest lane with the max
    int widx = __shfl(bi, wl, 64);    // wave-winner global index (wave-uniform)
    // ---- extract winner coords (uniform j select chain + shfl from owner lane) ------
    int jj = widx & (PPT-1);
    int ow = (widx >> 4) & 63;
    float sx=X[0].x, sy=Y[0].x, sz=Z[0].x;
    #pragma unroll
    for (int t=1;t<PPT;t++){
      bool sel = (jj==t);
      float xx = (t&1)? X[t>>1].y : X[t>>1].x;
      float yy = (t&1)? Y[t>>1].y : Y[t>>1].x;
      float zz = (t&1)? Z[t>>1].y : Z[t>>1].x;
      sx = sel? xx : sx; sy = sel? yy : sy; sz = sel? zz : sz;
    }
    sx = __shfl(sx, ow, 64);
    sy = __shfl(sy, ow, 64);
    sz = __shfl(sz, ow, 64);
    if (lane==0){
      // key packs (dist, ~idx): u64 max == argmax with lowest-index tie-break
      pkey[it&1][wid] = ((u64)__float_as_uint(wmax) << 32) | (u32)~(u32)widx;
      pxyz[it&1][wid] = make_float4(sx,sy,sz,0.0f);
    }
    __syncthreads();                  // only LDS outstanding -> cheap drain
    // ---- all threads redundantly reduce the NW partials (no second barrier) ---------
    u64 bk = pkey[it&1][0];
    float4 bc = pxyz[it&1][0];
    #pragma unroll
    for (int w=1;w<NW;w++){
      u64 k2 = pkey[it&1][w];
      float4 c2 = pxyz[it&1][w];
      if (k2 > bk){ bk=k2; bc=c2; }
    }
    cx=bc.x; cy=bc.y; cz=bc.z;
    if (tid==0) res[it] = bc;
  }
  __syncthreads();
  // ---- bulk store of all selected coords (both fp32 outputs) -----------------------
  for (int i=tid; i<SS; i+=FPT){
    float4 r = res[i];
    size_t o = (size_t)b*SS*3 + (size_t)i*3;
    out_xyz[o]=r.x; out_xyz[o+1]=r.y; out_xyz[o+2]=r.z;
    fps_xyz[o]=r.x; fps_xyz[o+1]=r.y; fps_xyz[o+2]=r.z;
  }
}

// ---------------- KNN: one wave per query, exact (q2+x2)-2dot, top-16 by (dist,idx) ----
__global__ __launch_bounds__(256) void k_knn(const float4* __restrict__ pts,
                                             const float* __restrict__ fps_xyz,
                                             int* __restrict__ knn_idx){
  int q = blockIdx.x*4 + (threadIdx.x>>6);
  int lane = threadIdx.x & 63;
  int b = q / SS;
  const float4* P = pts + (size_t)b*NN;
  float qx=fps_xyz[3*q], qy=fps_xyz[3*q+1], qz=fps_xyz[3*q+2];
  float q2 = __fadd_rn(__fadd_rn(__fmul_rn(qx,qx),__fmul_rn(qy,qy)),__fmul_rn(qz,qz));
  u64 key[KK];
  #pragma unroll
  for (int t=0;t<KK;t++) key[t] = ~0ull;
  for (int i=0;i<NN/64;i++){
    int n = i*64 + lane;             // coalesced float4 loads
    float4 p = P[n];
    float dot = __fadd_rn(__fadd_rn(__fmul_rn(qx,p.x),__fmul_rn(qy,p.y)),__fmul_rn(qz,p.z));
    float sd  = __fsub_rn(__fadd_rn(q2,p.w), __fmul_rn(2.0f,dot));
    u32 bu = __float_as_uint(sd);
    bu ^= (u32)((int)bu >> 31) | 0x80000000u;   // monotone float->uint (handles sd<0)
    u64 kk = ((u64)bu<<32) | (u32)n;
    if (kk < key[KK-1]){
      key[KK-1] = kk;
      #pragma unroll
      for (int t=KK-1;t>0;--t){      // one reverse bubble pass restores sortedness
        u64 a=key[t-1], c=key[t];
        bool sw = c < a;
        key[t-1] = sw? c : a;
        key[t]   = sw? a : c;
      }
    }
  }
  #pragma unroll 1
  for (int r=0;r<KK;r++){
    u64 m = key[0];
    #pragma unroll
    for (int mm=1;mm<64;mm<<=1){
      u64 om = __shfl_xor((unsigned long long)m, mm, 64);
      if (om < m) m = om;
    }
    if (lane==0) knn_idx[q*KK + r] = (int)(u32)m;
    if (key[0]==m){                  // unique keys -> exactly one lane pops
      #pragma unroll
      for (int t=0;t<KK-1;t++) key[t]=key[t+1];
      key[KK-1]=~0ull;
    }
  }
}

// ---------------- gather + MLP(67->128 relu ->128) + maxpool + LN, one wave/query ------
__global__ __launch_bounds__(256) void k_mlp(const float* __restrict__ feat,
                                             const float4* __restrict__ pts,
                                             const float* __restrict__ fps_xyz,
                                             const int* __restrict__ knn_idx,
                                             const float* __restrict__ W1, const float* __restrict__ b1,
                                             const float* __restrict__ W2, const float* __restrict__ b2,
                                             const float* __restrict__ g_ln, const float* __restrict__ b_ln,
                                             float* __restrict__ out_feat){
  __shared__ float gbuf[4][CIN][16];     // grouped: [j][k], wave-private slices
  __shared__ float hbuf[4][OD][20];      // h1: [channel][k], stride 20 (16B-aligned rows)
  int wid = threadIdx.x>>6, lane = threadIdx.x&63;
  int q = blockIdx.x*4 + wid;
  int b = q / SS;
  float* gw = &gbuf[wid][0][0];
  float* hw = &hbuf[wid][0][0];
  int k = lane & 15, part = lane >> 4;   // part in [0,4): 16 channels each
  int n = knn_idx[q*KK + k];
  {
    const float* fp = feat + ((size_t)b*NN + (size_t)n)*IND + part*16;
    float4 f0 = *(const float4*)(fp+0);
    float4 f1 = *(const float4*)(fp+4);
    float4 f2v = *(const float4*)(fp+8);
    float4 f3 = *(const float4*)(fp+12);
    float v[16] = {f0.x,f0.y,f0.z,f0.w, f1.x,f1.y,f1.z,f1.w,
                   f2v.x,f2v.y,f2v.z,f2v.w, f3.x,f3.y,f3.z,f3.w};
    #pragma unroll
    for (int c=0;c<16;c++) gw[(3+part*16+c)*16 + k] = v[c];
    if (part==0){
      float4 p = pts[(size_t)b*NN + n];
      gw[0*16+k] = __fsub_rn(p.x, fps_xyz[3*q+0]);  // exact rel coords (matches np fp32)
      gw[1*16+k] = __fsub_rn(p.y, fps_xyz[3*q+1]);
      gw[2*16+k] = __fsub_rn(p.z, fps_xyz[3*q+2]);
    }
  }
  __syncthreads();
  int o = lane;                          // this thread owns channels o and o+64
  float a0[16], a1[16];
  #pragma unroll
  for (int t=0;t<16;t++){ a0[t]=0.0f; a1[t]=0.0f; }
  #pragma unroll 4
  for (int j=0;j<CIN;j++){
    float w0 = W1[j*OD + o];
    float w1 = W1[j*OD + o + 64];
    #pragma unroll
    for (int t=0;t<16;t++){
      float gv = gw[j*16+t];             // LDS broadcast (merges to ds_read_b128)
      a0[t]=fmaf(gv,w0,a0[t]); a1[t]=fmaf(gv,w1,a1[t]);
    }
  }
  float bb0 = b1[o], bb1 = b1[o+64];
  #pragma unroll
  for (int t=0;t<16;t++){
    hw[o*20+t]      = fmaxf(a0[t]+bb0, 0.0f);
    hw[(o+64)*20+t] = fmaxf(a1[t]+bb1, 0.0f);
  }
  __syncthreads();
  float c0[16], c1[16];
  #pragma unroll
  for (int t=0;t<16;t++){ c0[t]=0.0f; c1[t]=0.0f; }
  #pragma unroll 4
  for (int j=0;j<OD;j++){
    float w0 = W2[j*OD + o];
    float w1 = W2[j*OD + o + 64];
    #pragma unroll
    for (int t=0;t<16;t++){
      float hv = hw[j*20+t];
      c0[t]=fmaf(hv,w0,c0[t]); c1[t]=fmaf(hv,w1,c1[t]);
    }
  }
  float m0=c0[0], m1=c1[0];
  #pragma unroll
  for (int t=1;t<16;t++){ m0=fmaxf(m0,c0[t]); m1=fmaxf(m1,c1[t]); }
  m0 += b2[o]; m1 += b2[o+64];           // fold bias after max (commutes with max)
  // LayerNorm over 128 channels (wave reduce)
  float ssum = m0+m1;
  #pragma unroll
  for (int mm=1;mm<64;mm<<=1) ssum += __shfl_xor(ssum,mm,64);
  float mean = ssum * (1.0f/128.0f);
  float d0=m0-mean, d1=m1-mean;
  float sq = d0*d0 + d1*d1;
  #pragma unroll
  for (int mm=1;mm<64;mm<<=1) sq += __shfl_xor(sq,mm,64);
  float var = sq * (1.0f/128.0f);
  float x = var + 1e-5f;
  float r = rsqrtf(x);
  r = r * (1.5f - 0.5f*x*r*r);           // one NR step -> ~1 ulp of 1/sqrt
  size_t ob = (size_t)q*OD;
  out_feat[ob+o]    = fmaf(d0*r, g_ln[o],    b_ln[o]);
  out_feat[ob+o+64] = fmaf(d1*r, g_ln[o+64], b_ln[o+64]);
}

extern "C" void kernel_launch(void* const* d_in, const int* in_sizes, int n_in,
                              void* d_out, int out_size, void* d_ws, size_t ws_size,
                              hipStream_t stream){
  const float* xyz  = (const float*)d_in[0];
  const float* feat = (const float*)d_in[1];
  const float* W1   = (const float*)d_in[2];
  const float* b1   = (const float*)d_in[3];
  const float* W2   = (const float*)d_in[4];
  const float* b2   = (const float*)d_in[5];
  const float* lg   = (const float*)d_in[6];
  const float* lb   = (const float*)d_in[7];
  float* out = (float*)d_out;
  char* ws = (char*)d_ws;
  float4* pts = (float4*)ws;                          // 512 KB
  float*  fpsx = (float*)(ws + 524288);               // 96 KB
  int*    kidx = (int*)(ws + 524288 + 98304);         // 512 KB
  float* out_xyz  = out;
  float* out_feat = out + (size_t)BB*SS*3;

  hipLaunchKernelGGL(k_prep, dim3((BB*NN+255)/256), dim3(256), 0, stream, xyz, pts);
  hipLaunchKernelGGL(k_fps,  dim3(BB),              dim3(FPT), 0, stream, pts, out_xyz, fpsx);
  hipLaunchKernelGGL(k_knn,  dim3(BB*SS/4),         dim3(256), 0, stream, pts, fpsx, kidx);
  hipLaunchKernelGGL(k_mlp,  dim3(BB*SS/4),         dim3(256), 0, stream,
                     feat, pts, fpsx, kidx, W1, b1, W2, b2, lg, lb, out_feat);
}

// Round 6
// 2467.591 us; speedup vs baseline: 1.5141x; 1.1795x over previous
//
#include <hip/hip_runtime.h>
#include <stdint.h>

#define BB 4
#define NN 8192
#define SS 2048
#define KK 16
#define IND 64
#define CIN 67
#define OD 128

typedef unsigned int   u32;
typedef unsigned long long u64;
typedef float f2 __attribute__((ext_vector_type(2)));

// ---------------- prep: pack xyz into float4(x,y,z,|p|^2) (rn ops, matches np sum order) -
__global__ __launch_bounds__(256) void k_prep(const float* __restrict__ xyz,
                                              float4* __restrict__ pts){
  int i = blockIdx.x * 256 + threadIdx.x;
  if (i >= BB*NN) return;
  float x = xyz[3*i+0];
  float y = xyz[3*i+1];
  float z = xyz[3*i+2];
  float x2 = __fadd_rn(__fadd_rn(__fmul_rn(x,x), __fmul_rn(y,y)), __fmul_rn(z,z));
  pts[i] = make_float4(x,y,z,x2);
}

// DPP helper: move x by DPP control, invalid lanes keep x (bound_ctrl=false -> old value)
template<int CTRL>
__device__ __forceinline__ float dpp_mv(float x){
  int xi = __builtin_bit_cast(int, x);
  int r  = __builtin_amdgcn_update_dpp(xi, xi, CTRL, 0xf, 0xf, false);
  return __builtin_bit_cast(float, r);
}

// ---------------- FPS v4: u64-key reduce only; winner coords via broadcast global load -
#define FPT 512
#define PPT (NN/FPT)   // 16 points per thread
#define NW  (FPT/64)   // 8 waves
__global__ __launch_bounds__(FPT) void k_fps(const float4* __restrict__ pts,
                                             float* __restrict__ out_xyz,
                                             float* __restrict__ fps_xyz){
  #pragma clang fp contract(off)
  __shared__ float4 res[SS];            // 32 KB: winner coords per iteration
  __shared__ u64    pkey[2][NW];        // double-buffered wave partial keys
  int b = blockIdx.x;
  int tid = threadIdx.x;
  int wid = tid >> 6, lane = tid & 63;
  const float4* P = pts + (size_t)b*NN;
  f2 X[PPT/2], Y[PPT/2], Z[PPT/2], D[PPT/2];
  #pragma unroll
  for (int jp=0;jp<PPT/2;jp++){
    float4 p0 = P[tid*PPT + 2*jp];
    float4 p1 = P[tid*PPT + 2*jp + 1];
    X[jp] = (f2){p0.x, p1.x};
    Y[jp] = (f2){p0.y, p1.y};
    Z[jp] = (f2){p0.z, p1.z};
    D[jp] = (f2){1e10f, 1e10f};
  }
  float4 pz0 = P[0];                    // broadcast load
  float cx=pz0.x, cy=pz0.y, cz=pz0.z;
  if (tid==0) res[0] = pz0;

  for (int it=1; it<SS; ++it){
    // ---- compute: plain fp32 ops under contract(off) == numpy rn semantics ----------
    float bd=-1.0f; int bj=0;
    #pragma unroll
    for (int jp=0;jp<PPT/2;jp++){
      f2 dx = X[jp] - cx;
      f2 dy = Y[jp] - cy;
      f2 dz = Z[jp] - cz;
      f2 d  = ((dx*dx) + (dy*dy)) + (dz*dz);   // ((dx2+dy2)+dz2), no fma
      f2 nd;
      nd.x = fminf(D[jp].x, d.x);
      nd.y = fminf(D[jp].y, d.y);
      D[jp] = nd;
      if (nd.x > bd){ bd=nd.x; bj=2*jp;   }    // strict > keeps first (lowest) index
      if (nd.y > bd){ bd=nd.y; bj=2*jp+1; }
    }
    int bi = tid*PPT + bj;
    // ---- wave max via DPP (6 ops), winner lane via ballot (lowest lane = lowest idx) -
    float m = bd;
    m = fmaxf(m, dpp_mv<0x111>(m));   // row_shr:1
    m = fmaxf(m, dpp_mv<0x112>(m));   // row_shr:2
    m = fmaxf(m, dpp_mv<0x114>(m));   // row_shr:4
    m = fmaxf(m, dpp_mv<0x118>(m));   // row_shr:8
    m = fmaxf(m, dpp_mv<0x142>(m));   // row_bcast:15
    m = fmaxf(m, dpp_mv<0x143>(m));   // row_bcast:31  -> lane 63 = wave max
    float wmax = __builtin_bit_cast(float,
        __builtin_amdgcn_readlane(__builtin_bit_cast(int, m), 63));
    u64 ball = __ballot(bd == wmax);
    int wl = __ffsll((unsigned long long)ball) - 1;  // lowest lane with the max
    int widx = __shfl(bi, wl, 64);    // wave-winner global index (wave-uniform)
    if (lane==0){
      // key packs (dist, ~idx): u64 max == argmax with lowest-index tie-break
      pkey[it&1][wid] = ((u64)__float_as_uint(wmax) << 32) | (u32)~(u32)widx;
    }
    __syncthreads();                  // only LDS outstanding -> cheap drain
    // ---- all threads reduce the 8 u64 partials (contiguous 64B -> vector ds_reads) --
    u64 bk = pkey[it&1][0];
    #pragma unroll
    for (int w=1;w<NW;w++){
      u64 k2 = pkey[it&1][w];
      if (k2 > bk) bk = k2;
    }
    int gw = (int)~(u32)bk;           // global winner index (block-uniform)
    // ---- broadcast fetch of winner coords: one transaction/wave, L1/L2 resident -----
    float4 c = P[gw];
    cx=c.x; cy=c.y; cz=c.z;
    if (tid==0) res[it] = c;
  }
  __syncthreads();
  // ---- bulk store of all selected coords (both fp32 outputs) -----------------------
  for (int i=tid; i<SS; i+=FPT){
    float4 r = res[i];
    size_t o = (size_t)b*SS*3 + (size_t)i*3;
    out_xyz[o]=r.x; out_xyz[o+1]=r.y; out_xyz[o+2]=r.z;
    fps_xyz[o]=r.x; fps_xyz[o+1]=r.y; fps_xyz[o+2]=r.z;
  }
}

// ---------------- KNN: one wave per query, exact (q2+x2)-2dot, top-16 by (dist,idx) ----
__global__ __launch_bounds__(256) void k_knn(const float4* __restrict__ pts,
                                             const float* __restrict__ fps_xyz,
                                             int* __restrict__ knn_idx){
  int q = blockIdx.x*4 + (threadIdx.x>>6);
  int lane = threadIdx.x & 63;
  int b = q / SS;
  const float4* P = pts + (size_t)b*NN;
  float qx=fps_xyz[3*q], qy=fps_xyz[3*q+1], qz=fps_xyz[3*q+2];
  float q2 = __fadd_rn(__fadd_rn(__fmul_rn(qx,qx),__fmul_rn(qy,qy)),__fmul_rn(qz,qz));
  u64 key[KK];
  #pragma unroll
  for (int t=0;t<KK;t++) key[t] = ~0ull;
  for (int i=0;i<NN/64;i++){
    int n = i*64 + lane;             // coalesced float4 loads
    float4 p = P[n];
    float dot = __fadd_rn(__fadd_rn(__fmul_rn(qx,p.x),__fmul_rn(qy,p.y)),__fmul_rn(qz,p.z));
    float sd  = __fsub_rn(__fadd_rn(q2,p.w), __fmul_rn(2.0f,dot));
    u32 bu = __float_as_uint(sd);
    bu ^= (u32)((int)bu >> 31) | 0x80000000u;   // monotone float->uint (handles sd<0)
    u64 kk = ((u64)bu<<32) | (u32)n;
    if (kk < key[KK-1]){
      key[KK-1] = kk;
      #pragma unroll
      for (int t=KK-1;t>0;--t){      // one reverse bubble pass restores sortedness
        u64 a=key[t-1], c=key[t];
        bool sw = c < a;
        key[t-1] = sw? c : a;
        key[t]   = sw? a : c;
      }
    }
  }
  #pragma unroll 1
  for (int r=0;r<KK;r++){
    u64 m = key[0];
    #pragma unroll
    for (int mm=1;mm<64;mm<<=1){
      u64 om = __shfl_xor((unsigned long long)m, mm, 64);
      if (om < m) m = om;
    }
    if (lane==0) knn_idx[q*KK + r] = (int)(u32)m;
    if (key[0]==m){                  // unique keys -> exactly one lane pops
      #pragma unroll
      for (int t=0;t<KK-1;t++) key[t]=key[t+1];
      key[KK-1]=~0ull;
    }
  }
}

// ---------------- gather + MLP(67->128 relu ->128) + maxpool + LN, one wave/query ------
__global__ __launch_bounds__(256) void k_mlp(const float* __restrict__ feat,
                                             const float4* __restrict__ pts,
                                             const float* __restrict__ fps_xyz,
                                             const int* __restrict__ knn_idx,
                                             const float* __restrict__ W1, const float* __restrict__ b1,
                                             const float* __restrict__ W2, const float* __restrict__ b2,
                                             const float* __restrict__ g_ln, const float* __restrict__ b_ln,
                                             float* __restrict__ out_feat){
  __shared__ float gbuf[4][CIN][16];     // grouped: [j][k], wave-private slices
  __shared__ float hbuf[4][OD][20];      // h1: [channel][k], stride 20 (16B-aligned rows)
  int wid = threadIdx.x>>6, lane = threadIdx.x&63;
  int q = blockIdx.x*4 + wid;
  int b = q / SS;
  float* gw = &gbuf[wid][0][0];
  float* hw = &hbuf[wid][0][0];
  int k = lane & 15, part = lane >> 4;   // part in [0,4): 16 channels each
  int n = knn_idx[q*KK + k];
  {
    const float* fp = feat + ((size_t)b*NN + (size_t)n)*IND + part*16;
    float4 f0 = *(const float4*)(fp+0);
    float4 f1 = *(const float4*)(fp+4);
    float4 f2v = *(const float4*)(fp+8);
    float4 f3 = *(const float4*)(fp+12);
    float v[16] = {f0.x,f0.y,f0.z,f0.w, f1.x,f1.y,f1.z,f1.w,
                   f2v.x,f2v.y,f2v.z,f2v.w, f3.x,f3.y,f3.z,f3.w};
    #pragma unroll
    for (int c=0;c<16;c++) gw[(3+part*16+c)*16 + k] = v[c];
    if (part==0){
      float4 p = pts[(size_t)b*NN + n];
      gw[0*16+k] = __fsub_rn(p.x, fps_xyz[3*q+0]);  // exact rel coords (matches np fp32)
      gw[1*16+k] = __fsub_rn(p.y, fps_xyz[3*q+1]);
      gw[2*16+k] = __fsub_rn(p.z, fps_xyz[3*q+2]);
    }
  }
  __syncthreads();
  int o = lane;                          // this thread owns channels o and o+64
  float a0[16], a1[16];
  #pragma unroll
  for (int t=0;t<16;t++){ a0[t]=0.0f; a1[t]=0.0f; }
  #pragma unroll 4
  for (int j=0;j<CIN;j++){
    float w0 = W1[j*OD + o];
    float w1 = W1[j*OD + o + 64];
    #pragma unroll
    for (int t=0;t<16;t++){
      float gv = gw[j*16+t];             // LDS broadcast (merges to ds_read_b128)
      a0[t]=fmaf(gv,w0,a0[t]); a1[t]=fmaf(gv,w1,a1[t]);
    }
  }
  float bb0 = b1[o], bb1 = b1[o+64];
  #pragma unroll
  for (int t=0;t<16;t++){
    hw[o*20+t]      = fmaxf(a0[t]+bb0, 0.0f);
    hw[(o+64)*20+t] = fmaxf(a1[t]+bb1, 0.0f);
  }
  __syncthreads();
  float c0[16], c1[16];
  #pragma unroll
  for (int t=0;t<16;t++){ c0[t]=0.0f; c1[t]=0.0f; }
  #pragma unroll 4
  for (int j=0;j<OD;j++){
    float w0 = W2[j*OD + o];
    float w1 = W2[j*OD + o + 64];
    #pragma unroll
    for (int t=0;t<16;t++){
      float hv = hw[j*20+t];
      c0[t]=fmaf(hv,w0,c0[t]); c1[t]=fmaf(hv,w1,c1[t]);
    }
  }
  float m0=c0[0], m1=c1[0];
  #pragma unroll
  for (int t=1;t<16;t++){ m0=fmaxf(m0,c0[t]); m1=fmaxf(m1,c1[t]); }
  m0 += b2[o]; m1 += b2[o+64];           // fold bias after max (commutes with max)
  // LayerNorm over 128 channels (wave reduce)
  float ssum = m0+m1;
  #pragma unroll
  for (int mm=1;mm<64;mm<<=1) ssum += __shfl_xor(ssum,mm,64);
  float mean = ssum * (1.0f/128.0f);
  float d0=m0-mean, d1=m1-mean;
  float sq = d0*d0 + d1*d1;
  #pragma unroll
  for (int mm=1;mm<64;mm<<=1) sq += __shfl_xor(sq,mm,64);
  float var = sq * (1.0f/128.0f);
  float x = var + 1e-5f;
  float r = rsqrtf(x);
  r = r * (1.5f - 0.5f*x*r*r);           // one NR step -> ~1 ulp of 1/sqrt
  size_t ob = (size_t)q*OD;
  out_feat[ob+o]    = fmaf(d0*r, g_ln[o],    b_ln[o]);
  out_feat[ob+o+64] = fmaf(d1*r, g_ln[o+64], b_ln[o+64]);
}

extern "C" void kernel_launch(void* const* d_in, const int* in_sizes, int n_in,
                              void* d_out, int out_size, void* d_ws, size_t ws_size,
                              hipStream_t stream){
  const float* xyz  = (const float*)d_in[0];
  const float* feat = (const float*)d_in[1];
  const float* W1   = (const float*)d_in[2];
  const float* b1   = (const float*)d_in[3];
  const float* W2   = (const float*)d_in[4];
  const float* b2   = (const float*)d_in[5];
  const float* lg   = (const float*)d_in[6];
  const float* lb   = (const float*)d_in[7];
  float* out = (float*)d_out;
  char* ws = (char*)d_ws;
  float4* pts = (float4*)ws;                          // 512 KB
  float*  fpsx = (float*)(ws + 524288);               // 96 KB
  int*    kidx = (int*)(ws + 524288 + 98304);         // 512 KB
  float* out_xyz  = out;
  float* out_feat = out + (size_t)BB*SS*3;

  hipLaunchKernelGGL(k_prep, dim3((BB*NN+255)/256), dim3(256), 0, stream, xyz, pts);
  hipLaunchKernelGGL(k_fps,  dim3(BB),              dim3(FPT), 0, stream, pts, out_xyz, fpsx);
  hipLaunchKernelGGL(k_knn,  dim3(BB*SS/4),         dim3(256), 0, stream, pts, fpsx, kidx);
  hipLaunchKernelGGL(k_mlp,  dim3(BB*SS/4),         dim3(256), 0, stream,
                     feat, pts, fpsx, kidx, W1, b1, W2, b2, lg, lb, out_feat);
}

// Round 7
// 2439.795 us; speedup vs baseline: 1.5314x; 1.0114x over previous
//
#include <hip/hip_runtime.h>
#include <stdint.h>

#define BB 4
#define NN 8192
#define SS 2048
#define KK 16
#define IND 64
#define CIN 67
#define OD 128

typedef unsigned int   u32;
typedef unsigned long long u64;
typedef float f2 __attribute__((ext_vector_type(2)));

// ---------------- prep: pack xyz into float4(x,y,z,|p|^2) (rn ops, matches np sum order) -
__global__ __launch_bounds__(256) void k_prep(const float* __restrict__ xyz,
                                              float4* __restrict__ pts){
  int i = blockIdx.x * 256 + threadIdx.x;
  if (i >= BB*NN) return;
  float x = xyz[3*i+0];
  float y = xyz[3*i+1];
  float z = xyz[3*i+2];
  float x2 = __fadd_rn(__fadd_rn(__fmul_rn(x,x), __fmul_rn(y,y)), __fmul_rn(z,z));
  pts[i] = make_float4(x,y,z,x2);
}

// DPP helper: move x by DPP control, invalid lanes keep x (bound_ctrl=false -> old value)
template<int CTRL>
__device__ __forceinline__ float dpp_mv(float x){
  int xi = __builtin_bit_cast(int, x);
  int r  = __builtin_amdgcn_update_dpp(xi, xi, CTRL, 0xf, 0xf, false);
  return __builtin_bit_cast(float, r);
}

// ---------------- FPS v5: packed min/max inner loop, deferred argmax recovery,
//                  coords in 96KB dynamic LDS, results streamed (retire under compute) ---
#define FPT 512
#define PPT (NN/FPT)   // 16 points per thread
#define NW  (FPT/64)   // 8 waves
__global__ __launch_bounds__(FPT) void k_fps(const float4* __restrict__ pts,
                                             float* __restrict__ out_xyz,
                                             float* __restrict__ fps_xyz){
  #pragma clang fp contract(off)
  extern __shared__ float smem[];       // sx[NN] | sy[NN] | sz[NN]  = 96 KB
  float* sx = smem;
  float* sy = smem +   NN;
  float* sz = smem + 2*NN;
  __shared__ u64 pkey[2][NW];           // double-buffered wave partial keys
  int b = blockIdx.x;
  int tid = threadIdx.x;
  int wid = tid >> 6, lane = tid & 63;
  const float4* P = pts + (size_t)b*NN;
  f2 X[PPT/2], Y[PPT/2], Z[PPT/2], D[PPT/2];
  #pragma unroll
  for (int jp=0;jp<PPT/2;jp++){
    int n0 = tid*PPT + 2*jp;
    float4 p0 = P[n0];
    float4 p1 = P[n0+1];
    X[jp] = (f2){p0.x, p1.x};
    Y[jp] = (f2){p0.y, p1.y};
    Z[jp] = (f2){p0.z, p1.z};
    D[jp] = (f2){1e10f, 1e10f};
    sx[n0]=p0.x; sx[n0+1]=p1.x;
    sy[n0]=p0.y; sy[n0+1]=p1.y;
    sz[n0]=p0.z; sz[n0+1]=p1.z;
  }
  float4 p0v = P[0];                    // broadcast load
  float cx=p0v.x, cy=p0v.y, cz=p0v.z;
  size_t ob = (size_t)b*SS*3;
  if (tid==0){
    out_xyz[ob+0]=cx; out_xyz[ob+1]=cy; out_xyz[ob+2]=cz;
    fps_xyz[ob+0]=cx; fps_xyz[ob+1]=cy; fps_xyz[ob+2]=cz;
  }
  __syncthreads();                      // LDS coords ready

  for (int it=1; it<SS; ++it){
    // ---- compute: pure packed math (v_pk_* are IEEE-rn per component; no fma) -------
    f2 mm = (f2){-1.0f, -1.0f};
    #pragma unroll
    for (int jp=0;jp<PPT/2;jp++){
      f2 dx = X[jp] - cx;
      f2 dy = Y[jp] - cy;
      f2 dz = Z[jp] - cz;
      f2 d  = ((dx*dx) + (dy*dy)) + (dz*dz);   // ((dx2+dy2)+dz2), no contraction
      f2 nd = __builtin_elementwise_min(D[jp], d);
      D[jp] = nd;
      mm = __builtin_elementwise_max(mm, nd);
    }
    float md = fmaxf(mm.x, mm.y);       // thread max (no index tracked)
    // ---- wave max via DPP (6 ops) ---------------------------------------------------
    float m = md;
    m = fmaxf(m, dpp_mv<0x111>(m));   // row_shr:1
    m = fmaxf(m, dpp_mv<0x112>(m));   // row_shr:2
    m = fmaxf(m, dpp_mv<0x114>(m));   // row_shr:4
    m = fmaxf(m, dpp_mv<0x118>(m));   // row_shr:8
    m = fmaxf(m, dpp_mv<0x142>(m));   // row_bcast:15
    m = fmaxf(m, dpp_mv<0x143>(m));   // row_bcast:31  -> lane 63 = wave max
    float wmax = __builtin_bit_cast(float,
        __builtin_amdgcn_readlane(__builtin_bit_cast(int, m), 63));
    // ---- deferred argmax recovery: lowest lane with md==wmax, first j within it -----
    u64 ball = __ballot(md == wmax);
    int wl = __ffsll((unsigned long long)ball) - 1;
    int bj = 0;
    if (md == wmax){
      #pragma unroll
      for (int t=PPT-1;t>=0;--t){       // descending overwrite -> lowest t wins
        float v = (t&1)? D[t>>1].y : D[t>>1].x;
        if (v == wmax) bj = t;
      }
    }
    int widx = __shfl(tid*PPT + bj, wl, 64);   // wave winner (wave-uniform)
    if (lane==0){
      // key packs (dist, ~idx): u64 max == argmax with lowest-index tie-break
      pkey[it&1][wid] = ((u64)__float_as_uint(wmax) << 32) | (u32)~(u32)widx;
    }
    __syncthreads();                    // only LDS outstanding -> cheap drain
    // ---- combine 8 u64 partials (contiguous 64B) ------------------------------------
    u64 bk = pkey[it&1][0];
    #pragma unroll
    for (int w=1;w<NW;w++){
      u64 k2 = pkey[it&1][w];
      if (k2 > bk) bk = k2;
    }
    int gw = (int)~(u32)bk;             // global winner index (block-uniform)
    // ---- winner coords from LDS (broadcast ds_read) ---------------------------------
    cx = sx[gw]; cy = sy[gw]; cz = sz[gw];
    if (tid==0){                        // fire-and-forget; retires under next compute
      size_t o = ob + (size_t)it*3;
      out_xyz[o]=cx; out_xyz[o+1]=cy; out_xyz[o+2]=cz;
      fps_xyz[o]=cx; fps_xyz[o+1]=cy; fps_xyz[o+2]=cz;
    }
  }
}

// ---------------- KNN: one wave per query, exact (q2+x2)-2dot, top-16 by (dist,idx) ----
__global__ __launch_bounds__(256) void k_knn(const float4* __restrict__ pts,
                                             const float* __restrict__ fps_xyz,
                                             int* __restrict__ knn_idx){
  int q = blockIdx.x*4 + (threadIdx.x>>6);
  int lane = threadIdx.x & 63;
  int b = q / SS;
  const float4* P = pts + (size_t)b*NN;
  float qx=fps_xyz[3*q], qy=fps_xyz[3*q+1], qz=fps_xyz[3*q+2];
  float q2 = __fadd_rn(__fadd_rn(__fmul_rn(qx,qx),__fmul_rn(qy,qy)),__fmul_rn(qz,qz));
  u64 key[KK];
  #pragma unroll
  for (int t=0;t<KK;t++) key[t] = ~0ull;
  for (int i=0;i<NN/64;i++){
    int n = i*64 + lane;             // coalesced float4 loads
    float4 p = P[n];
    float dot = __fadd_rn(__fadd_rn(__fmul_rn(qx,p.x),__fmul_rn(qy,p.y)),__fmul_rn(qz,p.z));
    float sd  = __fsub_rn(__fadd_rn(q2,p.w), __fmul_rn(2.0f,dot));
    u32 bu = __float_as_uint(sd);
    bu ^= (u32)((int)bu >> 31) | 0x80000000u;   // monotone float->uint (handles sd<0)
    u64 kk = ((u64)bu<<32) | (u32)n;
    if (kk < key[KK-1]){
      key[KK-1] = kk;
      #pragma unroll
      for (int t=KK-1;t>0;--t){      // one reverse bubble pass restores sortedness
        u64 a=key[t-1], c=key[t];
        bool sw = c < a;
        key[t-1] = sw? c : a;
        key[t]   = sw? a : c;
      }
    }
  }
  #pragma unroll 1
  for (int r=0;r<KK;r++){
    u64 m = key[0];
    #pragma unroll
    for (int mm=1;mm<64;mm<<=1){
      u64 om = __shfl_xor((unsigned long long)m, mm, 64);
      if (om < m) m = om;
    }
    if (lane==0) knn_idx[q*KK + r] = (int)(u32)m;
    if (key[0]==m){                  // unique keys -> exactly one lane pops
      #pragma unroll
      for (int t=0;t<KK-1;t++) key[t]=key[t+1];
      key[KK-1]=~0ull;
    }
  }
}

// ---------------- gather + MLP(67->128 relu ->128) + maxpool + LN, one wave/query ------
__global__ __launch_bounds__(256) void k_mlp(const float* __restrict__ feat,
                                             const float4* __restrict__ pts,
                                             const float* __restrict__ fps_xyz,
                                             const int* __restrict__ knn_idx,
                                             const float* __restrict__ W1, const float* __restrict__ b1,
                                             const float* __restrict__ W2, const float* __restrict__ b2,
                                             const float* __restrict__ g_ln, const float* __restrict__ b_ln,
                                             float* __restrict__ out_feat){
  __shared__ float gbuf[4][CIN][16];     // grouped: [j][k], wave-private slices
  __shared__ float hbuf[4][OD][20];      // h1: [channel][k], stride 20 (16B-aligned rows)
  int wid = threadIdx.x>>6, lane = threadIdx.x&63;
  int q = blockIdx.x*4 + wid;
  int b = q / SS;
  float* gw = &gbuf[wid][0][0];
  float* hw = &hbuf[wid][0][0];
  int k = lane & 15, part = lane >> 4;   // part in [0,4): 16 channels each
  int n = knn_idx[q*KK + k];
  {
    const float* fp = feat + ((size_t)b*NN + (size_t)n)*IND + part*16;
    float4 f0 = *(const float4*)(fp+0);
    float4 f1 = *(const float4*)(fp+4);
    float4 f2v = *(const float4*)(fp+8);
    float4 f3 = *(const float4*)(fp+12);
    float v[16] = {f0.x,f0.y,f0.z,f0.w, f1.x,f1.y,f1.z,f1.w,
                   f2v.x,f2v.y,f2v.z,f2v.w, f3.x,f3.y,f3.z,f3.w};
    #pragma unroll
    for (int c=0;c<16;c++) gw[(3+part*16+c)*16 + k] = v[c];
    if (part==0){
      float4 p = pts[(size_t)b*NN + n];
      gw[0*16+k] = __fsub_rn(p.x, fps_xyz[3*q+0]);  // exact rel coords (matches np fp32)
      gw[1*16+k] = __fsub_rn(p.y, fps_xyz[3*q+1]);
      gw[2*16+k] = __fsub_rn(p.z, fps_xyz[3*q+2]);
    }
  }
  __syncthreads();
  int o = lane;                          // this thread owns channels o and o+64
  float a0[16], a1[16];
  #pragma unroll
  for (int t=0;t<16;t++){ a0[t]=0.0f; a1[t]=0.0f; }
  #pragma unroll 4
  for (int j=0;j<CIN;j++){
    float w0 = W1[j*OD + o];
    float w1 = W1[j*OD + o + 64];
    #pragma unroll
    for (int t=0;t<16;t++){
      float gv = gw[j*16+t];             // LDS broadcast (merges to ds_read_b128)
      a0[t]=fmaf(gv,w0,a0[t]); a1[t]=fmaf(gv,w1,a1[t]);
    }
  }
  float bb0 = b1[o], bb1 = b1[o+64];
  #pragma unroll
  for (int t=0;t<16;t++){
    hw[o*20+t]      = fmaxf(a0[t]+bb0, 0.0f);
    hw[(o+64)*20+t] = fmaxf(a1[t]+bb1, 0.0f);
  }
  __syncthreads();
  float c0[16], c1[16];
  #pragma unroll
  for (int t=0;t<16;t++){ c0[t]=0.0f; c1[t]=0.0f; }
  #pragma unroll 4
  for (int j=0;j<OD;j++){
    float w0 = W2[j*OD + o];
    float w1 = W2[j*OD + o + 64];
    #pragma unroll
    for (int t=0;t<16;t++){
      float hv = hw[j*20+t];
      c0[t]=fmaf(hv,w0,c0[t]); c1[t]=fmaf(hv,w1,c1[t]);
    }
  }
  float m0=c0[0], m1=c1[0];
  #pragma unroll
  for (int t=1;t<16;t++){ m0=fmaxf(m0,c0[t]); m1=fmaxf(m1,c1[t]); }
  m0 += b2[o]; m1 += b2[o+64];           // fold bias after max (commutes with max)
  // LayerNorm over 128 channels (wave reduce)
  float ssum = m0+m1;
  #pragma unroll
  for (int mm=1;mm<64;mm<<=1) ssum += __shfl_xor(ssum,mm,64);
  float mean = ssum * (1.0f/128.0f);
  float d0=m0-mean, d1=m1-mean;
  float sq = d0*d0 + d1*d1;
  #pragma unroll
  for (int mm=1;mm<64;mm<<=1) sq += __shfl_xor(sq,mm,64);
  float var = sq * (1.0f/128.0f);
  float x = var + 1e-5f;
  float r = rsqrtf(x);
  r = r * (1.5f - 0.5f*x*r*r);           // one NR step -> ~1 ulp of 1/sqrt
  size_t obf = (size_t)q*OD;
  out_feat[obf+o]    = fmaf(d0*r, g_ln[o],    b_ln[o]);
  out_feat[obf+o+64] = fmaf(d1*r, g_ln[o+64], b_ln[o+64]);
}

extern "C" void kernel_launch(void* const* d_in, const int* in_sizes, int n_in,
                              void* d_out, int out_size, void* d_ws, size_t ws_size,
                              hipStream_t stream){
  const float* xyz  = (const float*)d_in[0];
  const float* feat = (const float*)d_in[1];
  const float* W1   = (const float*)d_in[2];
  const float* b1   = (const float*)d_in[3];
  const float* W2   = (const float*)d_in[4];
  const float* b2   = (const float*)d_in[5];
  const float* lg   = (const float*)d_in[6];
  const float* lb   = (const float*)d_in[7];
  float* out = (float*)d_out;
  char* ws = (char*)d_ws;
  float4* pts = (float4*)ws;                          // 512 KB
  float*  fpsx = (float*)(ws + 524288);               // 96 KB
  int*    kidx = (int*)(ws + 524288 + 98304);         // 512 KB
  float* out_xyz  = out;
  float* out_feat = out + (size_t)BB*SS*3;

  // allow 96 KB dynamic LDS for k_fps (gfx950: 160 KB/CU). Idempotent, capture-safe.
  hipFuncSetAttribute((const void*)k_fps,
                      hipFuncAttributeMaxDynamicSharedMemorySize, 3*NN*4);

  hipLaunchKernelGGL(k_prep, dim3((BB*NN+255)/256), dim3(256), 0, stream, xyz, pts);
  hipLaunchKernelGGL(k_fps,  dim3(BB),              dim3(FPT), 3*NN*4, stream, pts, out_xyz, fpsx);
  hipLaunchKernelGGL(k_knn,  dim3(BB*SS/4),         dim3(256), 0, stream, pts, fpsx, kidx);
  hipLaunchKernelGGL(k_mlp,  dim3(BB*SS/4),         dim3(256), 0, stream,
                     feat, pts, fpsx, kidx, W1, b1, W2, b2, lg, lb, out_feat);
}